// Round 1
// baseline (536.872 us; speedup 1.0000x reference)
//
#include <hip/hip_runtime.h>

typedef unsigned short u16;
typedef unsigned int u32;
typedef float f32x4 __attribute__((ext_vector_type(4)));
typedef short s16x8 __attribute__((ext_vector_type(8)));

#define T_ 4
#define B_ 16
#define C_ 512
#define N_ 1024
#define TB_ 64
#define YSZ 33554432  // 64*512*1024 (y output elements); attn follows in d_out

// ---- bf16 helpers (manual RNE, avoids HIP bf16 API differences) ----
__device__ __forceinline__ u16 f2bf(float f) {
  u32 u = __float_as_uint(f);
  u32 r = u + 0x7FFFu + ((u >> 16) & 1u);
  return (u16)(r >> 16);
}
__device__ __forceinline__ float bf2f(u16 h) { return __uint_as_float(((u32)h) << 16); }

// ---- async global->LDS, 16B per lane, wave-uniform LDS base ----
__device__ __forceinline__ void async16(const void* g, void* l) {
  __builtin_amdgcn_global_load_lds((const __attribute__((address_space(1))) void*)g,
                                   (__attribute__((address_space(3))) void*)l, 16, 0, 0);
}

// =====================================================================
// prep: split q_w/k_w into bf16 hi|lo concat [512][1024]; proj_w -> bf16;
//       BN constants (inv, bias) for q/k/p into consts[].
// =====================================================================
__global__ void prep_kernel(const float* __restrict__ qw, const float* __restrict__ kw,
                            const float* __restrict__ pw,
                            const float* __restrict__ qg, const float* __restrict__ qb,
                            const float* __restrict__ qm, const float* __restrict__ qv,
                            const float* __restrict__ kg, const float* __restrict__ kb,
                            const float* __restrict__ km, const float* __restrict__ kv,
                            const float* __restrict__ pg, const float* __restrict__ pbt,
                            const float* __restrict__ pm, const float* __restrict__ pv,
                            u16* __restrict__ whlq, u16* __restrict__ whlk,
                            u16* __restrict__ pwb, float* __restrict__ consts) {
  int blk = blockIdx.x, tid = threadIdx.x;
  if (blk < 512) {
    int d = blk;
    for (int c = tid; c < 512; c += 256) {
      float w = qw[d * 512 + c];
      u16 hi = f2bf(w);
      whlq[d * 1024 + c] = hi;
      whlq[d * 1024 + 512 + c] = f2bf(w - bf2f(hi));
      w = kw[d * 512 + c];
      hi = f2bf(w);
      whlk[d * 1024 + c] = hi;
      whlk[d * 1024 + 512 + c] = f2bf(w - bf2f(hi));
      pwb[d * 512 + c] = f2bf(pw[d * 512 + c]);
    }
  } else {
    for (int c = tid; c < 512; c += 256) {
      float inv = qg[c] / sqrtf(qv[c] + 1e-5f);
      consts[c] = inv; consts[512 + c] = qb[c] - qm[c] * inv;
      inv = kg[c] / sqrtf(kv[c] + 1e-5f);
      consts[1024 + c] = inv; consts[1536 + c] = kb[c] - km[c] * inv;
      inv = pg[c] / sqrtf(pv[c] + 1e-5f);
      consts[2048 + c] = inv; consts[2560 + c] = pbt[c] - pm[c] * inv;
    }
  }
}

// =====================================================================
// lif_x: x[t,b,c,n] f32 -> spikes xs[t,b,n,c] bf16 (LDS transpose).
// Block: (ntile64, ctile64, b). Thread: c_l=tid>>6 handles 16 c, n=tid&63.
// =====================================================================
__global__ __launch_bounds__(256) void lifx_kernel(const float* __restrict__ x,
                                                   u16* __restrict__ xs) {
  int b = blockIdx.z;
  int cbase = blockIdx.y * 64, nbase = blockIdx.x * 64;
  int tid = threadIdx.x;
  int c_l = tid >> 6, n_l = tid & 63;
  __shared__ __align__(16) u16 tile[64 * 72];
  float v[16];
#pragma unroll
  for (int i = 0; i < 16; ++i) v[i] = 0.f;
  for (int t = 0; t < 4; ++t) {
    const float* xp = x + ((size_t)(t * 16 + b) * 512 + cbase + c_l * 16) * 1024 + nbase + n_l;
#pragma unroll
    for (int i = 0; i < 16; ++i) {
      float xv = xp[(size_t)i * 1024];
      float vn = v[i] + 0.5f * (xv - v[i]);   // v + (x-v)/TAU, TAU=2 (bit-exact vs np)
      bool s = vn >= 1.0f;
      tile[n_l * 72 + c_l * 16 + i] = s ? 0x3F80 : 0;
      v[i] = s ? 0.f : vn;
    }
    __syncthreads();
    u16* yb = xs + ((size_t)(t * 16 + b) * 1024 + nbase) * 512 + cbase;
#pragma unroll
    for (int e = 0; e < 2; ++e) {
      int chunk = tid * 2 + e;
      int n = chunk >> 3, c0 = (chunk & 7) * 8;
      *(uint4*)&yb[(size_t)n * 512 + c0] = *(const uint4*)&tile[n * 72 + c0];
    }
    __syncthreads();
  }
}

// =====================================================================
// q-pass: conv_q -> BN -> LIF(vth=1) -> head-sum qh -> LIF(vth=0.5) -> attn
// attn written to d_out tail (f32 0/1). Block: (ntile256, h, b).
// =====================================================================
__global__ __launch_bounds__(256) void qpass_kernel(const float* __restrict__ conv,
                                                    const float* __restrict__ consts,
                                                    float* __restrict__ dout) {
  int b = blockIdx.z, h = blockIdx.y;
  int n = blockIdx.x * 256 + threadIdx.x;
  const float* qinv = consts;
  const float* qbias = consts + 512;
  float qh[4] = {0.f, 0.f, 0.f, 0.f};
  for (int dh = 0; dh < 64; ++dh) {
    int c = h * 64 + dh;
    float iv = qinv[c], ib = qbias[c];
    float v = 0.f;
#pragma unroll
    for (int t = 0; t < 4; ++t) {
      float cv = conv[((size_t)(t * 16 + b) * 512 + c) * 1024 + n];
      float bnv = cv * iv + ib;
      float vn = v + 0.5f * (bnv - v);
      bool s = vn >= 1.0f;
      qh[t] += s ? 1.f : 0.f;
      v = s ? 0.f : vn;
    }
  }
  float va = 0.f;
#pragma unroll
  for (int t = 0; t < 4; ++t) {
    float vn = va + 0.5f * (qh[t] - va);   // exact dyadic arithmetic, no flip risk
    bool s = vn >= 0.5f;
    dout[(size_t)YSZ + ((size_t)(t * 16 + b) * 8 + h) * 1024 + n] = s ? 1.f : 0.f;
    va = s ? 0.f : vn;
  }
}

// =====================================================================
// k-pass: conv_k -> BN -> LIF(vth=1) -> y = spike * attn -> y[t,b,n,c] bf16
// (LDS transpose, same structure as lifx). Block: (ntile64, h(=ctile64), b).
// =====================================================================
__global__ __launch_bounds__(256) void kpass_kernel(const float* __restrict__ conv,
                                                    const float* __restrict__ consts,
                                                    const float* __restrict__ dout,
                                                    u16* __restrict__ y) {
  int b = blockIdx.z, h = blockIdx.y;
  int cbase = h * 64, nbase = blockIdx.x * 64;
  int tid = threadIdx.x;
  int c_l = tid >> 6, n_l = tid & 63;
  const float* kinv = consts + 1024;
  const float* kbias = consts + 1536;
  __shared__ __align__(16) u16 tile[64 * 72];
  float v[16], iv[16], ib[16];
#pragma unroll
  for (int i = 0; i < 16; ++i) {
    v[i] = 0.f;
    iv[i] = kinv[cbase + c_l * 16 + i];
    ib[i] = kbias[cbase + c_l * 16 + i];
  }
  for (int t = 0; t < 4; ++t) {
    float a = dout[(size_t)YSZ + ((size_t)(t * 16 + b) * 8 + h) * 1024 + nbase + n_l];
    const float* cp = conv + ((size_t)(t * 16 + b) * 512 + cbase + c_l * 16) * 1024 + nbase + n_l;
#pragma unroll
    for (int i = 0; i < 16; ++i) {
      float bnv = cp[(size_t)i * 1024] * iv[i] + ib[i];
      float vn = v[i] + 0.5f * (bnv - v[i]);
      bool s = vn >= 1.0f;
      tile[n_l * 72 + c_l * 16 + i] = (s && a != 0.f) ? 0x3F80 : 0;
      v[i] = s ? 0.f : vn;
    }
    __syncthreads();
    u16* yb = y + ((size_t)(t * 16 + b) * 1024 + nbase) * 512 + cbase;
#pragma unroll
    for (int e = 0; e < 2; ++e) {
      int chunk = tid * 2 + e;
      int n = chunk >> 3, c0 = (chunk & 7) * 8;
      *(uint4*)&yb[(size_t)n * 512 + c0] = *(const uint4*)&tile[n * 72 + c0];
    }
    __syncthreads();
  }
}

// =====================================================================
// GEMM (m97 structure): out[d,n] = sum_k A[d,k]*B[n,k], per tb batch.
// A: bf16 [M][lda] row-major (k contig). B: bf16 [tb][1024 n][512 c], k-index
// masked &511 (hi|lo split re-reads same spikes). 128x128 tile, BK=64,
// 4 waves each 64x64, 16x16x32 bf16 MFMA, global_load_lds width=16.
// MODE 0: store raw f32 acc to conv[tb][512][1024].
// MODE 1: (acc + proj_b)*p_inv + p_bias -> d_out.
// =====================================================================
template <int MODE>
__global__ __launch_bounds__(256, 3) void gemm_kernel(
    const u16* __restrict__ A, int lda, int K, const u16* __restrict__ Bbase,
    float* __restrict__ outC, float* __restrict__ outP,
    const float* __restrict__ projb, const float* __restrict__ consts) {
  const int tid = threadIdx.x;
  const int lane = tid & 63, w = tid >> 6;
  const int wm = w >> 1, wn = w & 1;
  const int quad = lane >> 4, l16 = lane & 15;
  const int tb = blockIdx.z;
  const int m_blk = blockIdx.y * 128, n_blk = blockIdx.x * 128;
  const int srow = lane >> 3, scol = (lane & 7) * 8;
  __shared__ __align__(16) u16 As[128 * 64];
  __shared__ __align__(16) u16 Bs[128 * 64];
  f32x4 acc[4][4];
  const f32x4 zero = {0.f, 0.f, 0.f, 0.f};
#pragma unroll
  for (int i = 0; i < 4; ++i)
#pragma unroll
    for (int j = 0; j < 4; ++j) acc[i][j] = zero;
  const u16* Bt = Bbase + (size_t)tb * (N_ * C_);

  for (int k0 = 0; k0 < K; k0 += 64) {
    int ck0 = k0 & 511;
#pragma unroll
    for (int i = 0; i < 4; ++i) {
      int r = i * 32 + w * 8 + srow;
      async16(A + (size_t)(m_blk + r) * lda + k0 + scol, &As[(i * 32 + w * 8) * 64]);
      async16(Bt + (size_t)(n_blk + r) * 512 + ck0 + scol, &Bs[(i * 32 + w * 8) * 64]);
    }
    __syncthreads();
#pragma unroll
    for (int kk = 0; kk < 2; ++kk) {
      s16x8 af[4], bf[4];
#pragma unroll
      for (int ti = 0; ti < 4; ++ti)
        af[ti] = *(const s16x8*)&As[(wm * 64 + ti * 16 + l16) * 64 + kk * 32 + quad * 8];
#pragma unroll
      for (int tj = 0; tj < 4; ++tj)
        bf[tj] = *(const s16x8*)&Bs[(wn * 64 + tj * 16 + l16) * 64 + kk * 32 + quad * 8];
#pragma unroll
      for (int ti = 0; ti < 4; ++ti)
#pragma unroll
        for (int tj = 0; tj < 4; ++tj)
          acc[ti][tj] = __builtin_amdgcn_mfma_f32_16x16x32_bf16(af[ti], bf[tj], acc[ti][tj], 0, 0, 0);
    }
    __syncthreads();
  }

  if (MODE == 0) {
    float* o = outC + (size_t)tb * (C_ * N_);
#pragma unroll
    for (int ti = 0; ti < 4; ++ti) {
      int row0 = m_blk + wm * 64 + ti * 16 + quad * 4;
#pragma unroll
      for (int tj = 0; tj < 4; ++tj) {
        int col = n_blk + wn * 64 + tj * 16 + l16;
#pragma unroll
        for (int r = 0; r < 4; ++r) o[(size_t)(row0 + r) * N_ + col] = acc[ti][tj][r];
      }
    }
  } else {
    const float* pinv = consts + 2048;
    const float* pb2 = consts + 2560;
    float* o = outP + (size_t)tb * (C_ * N_);
#pragma unroll
    for (int ti = 0; ti < 4; ++ti) {
      int row0 = m_blk + wm * 64 + ti * 16 + quad * 4;
#pragma unroll
      for (int r = 0; r < 4; ++r) {
        int row = row0 + r;
        float bi = projb[row], piv = pinv[row], pbi = pb2[row];
#pragma unroll
        for (int tj = 0; tj < 4; ++tj) {
          int col = n_blk + wn * 64 + tj * 16 + l16;
          o[(size_t)row * N_ + col] = (acc[ti][tj][r] + bi) * piv + pbi;
        }
      }
    }
  }
}

// =====================================================================
extern "C" void kernel_launch(void* const* d_in, const int* in_sizes, int n_in,
                              void* d_out, int out_size, void* d_ws, size_t ws_size,
                              hipStream_t stream) {
  const float* x   = (const float*)d_in[0];
  const float* qw  = (const float*)d_in[1];
  const float* qg  = (const float*)d_in[2];
  const float* qb  = (const float*)d_in[3];
  const float* qm  = (const float*)d_in[4];
  const float* qv  = (const float*)d_in[5];
  const float* kw  = (const float*)d_in[6];
  const float* kg  = (const float*)d_in[7];
  const float* kb  = (const float*)d_in[8];
  const float* km  = (const float*)d_in[9];
  const float* kv  = (const float*)d_in[10];
  const float* pw  = (const float*)d_in[11];
  const float* pb  = (const float*)d_in[12];
  const float* pg  = (const float*)d_in[13];
  const float* pbt = (const float*)d_in[14];
  const float* pm  = (const float*)d_in[15];
  const float* pv  = (const float*)d_in[16];
  float* out = (float*)d_out;
  char* ws = (char*)d_ws;

  // ws layout (bytes): xs/y bf16 [64][1024][512] @0 (67,108,864)
  //                    conv f32 [64][512][1024] @67,108,864 (134,217,728)
  //                    whlq @201,326,592 (1 MB) | whlk @202,375,168 (1 MB)
  //                    pwb  @203,423,744 (0.5 MB) | consts @203,948,032
  u16* xs       = (u16*)ws;
  float* conv   = (float*)(ws + 67108864);
  u16* whlq     = (u16*)(ws + 201326592);
  u16* whlk     = (u16*)(ws + 202375168);
  u16* pwb      = (u16*)(ws + 203423744);
  float* consts = (float*)(ws + 203948032);

  prep_kernel<<<513, 256, 0, stream>>>(qw, kw, pw, qg, qb, qm, qv, kg, kb, km, kv,
                                       pg, pbt, pm, pv, whlq, whlk, pwb, consts);
  lifx_kernel<<<dim3(16, 8, 16), 256, 0, stream>>>(x, xs);
  gemm_kernel<0><<<dim3(8, 4, 64), 256, 0, stream>>>(whlq, 1024, 1024, xs, conv,
                                                     nullptr, nullptr, nullptr);
  qpass_kernel<<<dim3(4, 8, 16), 256, 0, stream>>>(conv, consts, out);
  gemm_kernel<0><<<dim3(8, 4, 64), 256, 0, stream>>>(whlk, 1024, 1024, xs, conv,
                                                     nullptr, nullptr, nullptr);
  kpass_kernel<<<dim3(16, 8, 16), 256, 0, stream>>>(conv, consts, out, xs);  // y overwrites xs
  gemm_kernel<1><<<dim3(8, 4, 64), 256, 0, stream>>>(pwb, 512, 512, xs, nullptr, out,
                                                     pb, consts);
}

// Round 2
// 483.858 us; speedup vs baseline: 1.1096x; 1.1096x over previous
//
#include <hip/hip_runtime.h>

typedef unsigned short u16;
typedef unsigned int u32;
typedef float f32x4 __attribute__((ext_vector_type(4)));
typedef short s16x8 __attribute__((ext_vector_type(8)));

#define T_ 4
#define B_ 16
#define C_ 512
#define N_ 1024
#define TB_ 64
#define YSZ 33554432  // 64*512*1024 (y output elements); attn follows in d_out

// ---- bf16 helpers (manual RNE) ----
__device__ __forceinline__ u16 f2bf(float f) {
  u32 u = __float_as_uint(f);
  u32 r = u + 0x7FFFu + ((u >> 16) & 1u);
  return (u16)(r >> 16);
}
__device__ __forceinline__ float bf2f(u16 h) { return __uint_as_float(((u32)h) << 16); }

// ---- async global->LDS, 16B per lane, wave-uniform LDS base ----
__device__ __forceinline__ void async16(const void* g, void* l) {
  __builtin_amdgcn_global_load_lds((const __attribute__((address_space(1))) void*)g,
                                   (__attribute__((address_space(3))) void*)l, 16, 0, 0);
}

// =====================================================================
// prep: split q_w/k_w into bf16 hi|lo concat [512][1024]; proj_w -> bf16;
//       BN constants (inv, bias) for q/k/p into consts[].
// =====================================================================
__global__ void prep_kernel(const float* __restrict__ qw, const float* __restrict__ kw,
                            const float* __restrict__ pw,
                            const float* __restrict__ qg, const float* __restrict__ qb,
                            const float* __restrict__ qm, const float* __restrict__ qv,
                            const float* __restrict__ kg, const float* __restrict__ kb,
                            const float* __restrict__ km, const float* __restrict__ kv,
                            const float* __restrict__ pg, const float* __restrict__ pbt,
                            const float* __restrict__ pm, const float* __restrict__ pv,
                            u16* __restrict__ whlq, u16* __restrict__ whlk,
                            u16* __restrict__ pwb, float* __restrict__ consts) {
  int blk = blockIdx.x, tid = threadIdx.x;
  if (blk < 512) {
    int d = blk;
    for (int c = tid; c < 512; c += 256) {
      float w = qw[d * 512 + c];
      u16 hi = f2bf(w);
      whlq[d * 1024 + c] = hi;
      whlq[d * 1024 + 512 + c] = f2bf(w - bf2f(hi));
      w = kw[d * 512 + c];
      hi = f2bf(w);
      whlk[d * 1024 + c] = hi;
      whlk[d * 1024 + 512 + c] = f2bf(w - bf2f(hi));
      pwb[d * 512 + c] = f2bf(pw[d * 512 + c]);
    }
  } else {
    for (int c = tid; c < 512; c += 256) {
      float inv = qg[c] / sqrtf(qv[c] + 1e-5f);
      consts[c] = inv; consts[512 + c] = qb[c] - qm[c] * inv;
      inv = kg[c] / sqrtf(kv[c] + 1e-5f);
      consts[1024 + c] = inv; consts[1536 + c] = kb[c] - km[c] * inv;
      inv = pg[c] / sqrtf(pv[c] + 1e-5f);
      consts[2048 + c] = inv; consts[2560 + c] = pbt[c] - pm[c] * inv;
    }
  }
}

// =====================================================================
// lif_x: x[t,b,c,n] f32 -> spikes xs[t,b,n,c] bf16 (LDS transpose).
// =====================================================================
__global__ __launch_bounds__(256) void lifx_kernel(const float* __restrict__ x,
                                                   u16* __restrict__ xs) {
  int b = blockIdx.z;
  int cbase = blockIdx.y * 64, nbase = blockIdx.x * 64;
  int tid = threadIdx.x;
  int c_l = tid >> 6, n_l = tid & 63;
  __shared__ __align__(16) u16 tile[64 * 72];
  float v[16];
#pragma unroll
  for (int i = 0; i < 16; ++i) v[i] = 0.f;
  for (int t = 0; t < 4; ++t) {
    const float* xp = x + ((size_t)(t * 16 + b) * 512 + cbase + c_l * 16) * 1024 + nbase + n_l;
#pragma unroll
    for (int i = 0; i < 16; ++i) {
      float xv = xp[(size_t)i * 1024];
      float vn = v[i] + 0.5f * (xv - v[i]);   // v + (x-v)/TAU, TAU=2 (bit-exact vs np)
      bool s = vn >= 1.0f;
      tile[n_l * 72 + c_l * 16 + i] = s ? 0x3F80 : 0;
      v[i] = s ? 0.f : vn;
    }
    __syncthreads();
    u16* yb = xs + ((size_t)(t * 16 + b) * 1024 + nbase) * 512 + cbase;
#pragma unroll
    for (int e = 0; e < 2; ++e) {
      int chunk = tid * 2 + e;
      int n = chunk >> 3, c0 = (chunk & 7) * 8;
      *(uint4*)&yb[(size_t)n * 512 + c0] = *(const uint4*)&tile[n * 72 + c0];
    }
    __syncthreads();
  }
}

// =====================================================================
// q-pass: conv_q -> BN -> LIF(vth=1) -> head-sum qh -> LIF(vth=0.5) -> attn
// =====================================================================
__global__ __launch_bounds__(256) void qpass_kernel(const float* __restrict__ conv,
                                                    const float* __restrict__ consts,
                                                    float* __restrict__ dout) {
  int b = blockIdx.z, h = blockIdx.y;
  int n = blockIdx.x * 256 + threadIdx.x;
  const float* qinv = consts;
  const float* qbias = consts + 512;
  float qh[4] = {0.f, 0.f, 0.f, 0.f};
  for (int dh = 0; dh < 64; ++dh) {
    int c = h * 64 + dh;
    float iv = qinv[c], ib = qbias[c];
    float v = 0.f;
#pragma unroll
    for (int t = 0; t < 4; ++t) {
      float cv = conv[((size_t)(t * 16 + b) * 512 + c) * 1024 + n];
      float bnv = cv * iv + ib;
      float vn = v + 0.5f * (bnv - v);
      bool s = vn >= 1.0f;
      qh[t] += s ? 1.f : 0.f;
      v = s ? 0.f : vn;
    }
  }
  float va = 0.f;
#pragma unroll
  for (int t = 0; t < 4; ++t) {
    float vn = va + 0.5f * (qh[t] - va);
    bool s = vn >= 0.5f;
    dout[(size_t)YSZ + ((size_t)(t * 16 + b) * 8 + h) * 1024 + n] = s ? 1.f : 0.f;
    va = s ? 0.f : vn;
  }
}

// =====================================================================
// k-pass: conv_k -> BN -> LIF(vth=1) -> y = spike * attn -> y[t,b,n,c] bf16
// =====================================================================
__global__ __launch_bounds__(256) void kpass_kernel(const float* __restrict__ conv,
                                                    const float* __restrict__ consts,
                                                    const float* __restrict__ dout,
                                                    u16* __restrict__ y) {
  int b = blockIdx.z, h = blockIdx.y;
  int cbase = h * 64, nbase = blockIdx.x * 64;
  int tid = threadIdx.x;
  int c_l = tid >> 6, n_l = tid & 63;
  const float* kinv = consts + 1024;
  const float* kbias = consts + 1536;
  __shared__ __align__(16) u16 tile[64 * 72];
  float v[16], iv[16], ib[16];
#pragma unroll
  for (int i = 0; i < 16; ++i) {
    v[i] = 0.f;
    iv[i] = kinv[cbase + c_l * 16 + i];
    ib[i] = kbias[cbase + c_l * 16 + i];
  }
  for (int t = 0; t < 4; ++t) {
    float a = dout[(size_t)YSZ + ((size_t)(t * 16 + b) * 8 + h) * 1024 + nbase + n_l];
    const float* cp = conv + ((size_t)(t * 16 + b) * 512 + cbase + c_l * 16) * 1024 + nbase + n_l;
#pragma unroll
    for (int i = 0; i < 16; ++i) {
      float bnv = cp[(size_t)i * 1024] * iv[i] + ib[i];
      float vn = v[i] + 0.5f * (bnv - v[i]);
      bool s = vn >= 1.0f;
      tile[n_l * 72 + c_l * 16 + i] = (s && a != 0.f) ? 0x3F80 : 0;
      v[i] = s ? 0.f : vn;
    }
    __syncthreads();
    u16* yb = y + ((size_t)(t * 16 + b) * 1024 + nbase) * 512 + cbase;
#pragma unroll
    for (int e = 0; e < 2; ++e) {
      int chunk = tid * 2 + e;
      int n = chunk >> 3, c0 = (chunk & 7) * 8;
      *(uint4*)&yb[(size_t)n * 512 + c0] = *(const uint4*)&tile[n * 72 + c0];
    }
    __syncthreads();
  }
}

// =====================================================================
// GEMM (m97 structure + XOR bank-swizzle): out[d,n] = sum_k A[d,k]*B[n,k].
// LDS rows are 64 u16 = 8 chunks of 16B. Chunk at slot s of row r holds
// global chunk s ^ (r&7): staging permutes the GLOBAL k-offset per lane
// (global_load_lds LDS dst must stay contiguous), fragment reads address
// slot (c ^ (r&7)). Breaks the 16-way same-bank conflict of stride-128B
// rows (bank = ((c^r)&7)*4 -> 2-way only, free per m136).
// MODE 0: store raw f32 acc to conv. MODE 1: proj epilogue -> d_out.
// =====================================================================
template <int MODE>
__global__ __launch_bounds__(256, 3) void gemm_kernel(
    const u16* __restrict__ A, int lda, int K, const u16* __restrict__ Bbase,
    float* __restrict__ outC, float* __restrict__ outP,
    const float* __restrict__ projb, const float* __restrict__ consts) {
  const int tid = threadIdx.x;
  const int lane = tid & 63, w = tid >> 6;
  const int wm = w >> 1, wn = w & 1;
  const int quad = lane >> 4, l16 = lane & 15;
  const int tb = blockIdx.z;
  const int m_blk = blockIdx.y * 128, n_blk = blockIdx.x * 128;
  const int srow = lane >> 3;
  const int scol = (((lane & 7) ^ srow) & 7) * 8;  // swizzled global chunk
  __shared__ __align__(16) u16 As[128 * 64];
  __shared__ __align__(16) u16 Bs[128 * 64];
  f32x4 acc[4][4];
  const f32x4 zero = {0.f, 0.f, 0.f, 0.f};
#pragma unroll
  for (int i = 0; i < 4; ++i)
#pragma unroll
    for (int j = 0; j < 4; ++j) acc[i][j] = zero;
  const u16* Bt = Bbase + (size_t)tb * (N_ * C_);
  const int rxor = l16 & 7;  // fragment row mod 8 (wm*64, ti*16 are mult of 8)

  for (int k0 = 0; k0 < K; k0 += 64) {
    int ck0 = k0 & 511;
#pragma unroll
    for (int i = 0; i < 4; ++i) {
      int r = i * 32 + w * 8 + srow;
      async16(A + (size_t)(m_blk + r) * lda + k0 + scol, &As[(i * 32 + w * 8) * 64]);
      async16(Bt + (size_t)(n_blk + r) * 512 + ck0 + scol, &Bs[(i * 32 + w * 8) * 64]);
    }
    __syncthreads();
#pragma unroll
    for (int kk = 0; kk < 2; ++kk) {
      s16x8 af[4], bf[4];
      const int slot = ((kk * 4 + quad) ^ rxor) * 8;  // swizzled LDS chunk
#pragma unroll
      for (int ti = 0; ti < 4; ++ti)
        af[ti] = *(const s16x8*)&As[(wm * 64 + ti * 16 + l16) * 64 + slot];
#pragma unroll
      for (int tj = 0; tj < 4; ++tj)
        bf[tj] = *(const s16x8*)&Bs[(wn * 64 + tj * 16 + l16) * 64 + slot];
#pragma unroll
      for (int ti = 0; ti < 4; ++ti)
#pragma unroll
        for (int tj = 0; tj < 4; ++tj)
          acc[ti][tj] = __builtin_amdgcn_mfma_f32_16x16x32_bf16(af[ti], bf[tj], acc[ti][tj], 0, 0, 0);
    }
    __syncthreads();
  }

  if (MODE == 0) {
    float* o = outC + (size_t)tb * (C_ * N_);
#pragma unroll
    for (int ti = 0; ti < 4; ++ti) {
      int row0 = m_blk + wm * 64 + ti * 16 + quad * 4;
#pragma unroll
      for (int tj = 0; tj < 4; ++tj) {
        int col = n_blk + wn * 64 + tj * 16 + l16;
#pragma unroll
        for (int r = 0; r < 4; ++r) o[(size_t)(row0 + r) * N_ + col] = acc[ti][tj][r];
      }
    }
  } else {
    const float* pinv = consts + 2048;
    const float* pb2 = consts + 2560;
    float* o = outP + (size_t)tb * (C_ * N_);
#pragma unroll
    for (int ti = 0; ti < 4; ++ti) {
      int row0 = m_blk + wm * 64 + ti * 16 + quad * 4;
#pragma unroll
      for (int r = 0; r < 4; ++r) {
        int row = row0 + r;
        float bi = projb[row], piv = pinv[row], pbi = pb2[row];
#pragma unroll
        for (int tj = 0; tj < 4; ++tj) {
          int col = n_blk + wn * 64 + tj * 16 + l16;
          o[(size_t)row * N_ + col] = (acc[ti][tj][r] + bi) * piv + pbi;
        }
      }
    }
  }
}

// =====================================================================
extern "C" void kernel_launch(void* const* d_in, const int* in_sizes, int n_in,
                              void* d_out, int out_size, void* d_ws, size_t ws_size,
                              hipStream_t stream) {
  const float* x   = (const float*)d_in[0];
  const float* qw  = (const float*)d_in[1];
  const float* qg  = (const float*)d_in[2];
  const float* qb  = (const float*)d_in[3];
  const float* qm  = (const float*)d_in[4];
  const float* qv  = (const float*)d_in[5];
  const float* kw  = (const float*)d_in[6];
  const float* kg  = (const float*)d_in[7];
  const float* kb  = (const float*)d_in[8];
  const float* km  = (const float*)d_in[9];
  const float* kv  = (const float*)d_in[10];
  const float* pw  = (const float*)d_in[11];
  const float* pb  = (const float*)d_in[12];
  const float* pg  = (const float*)d_in[13];
  const float* pbt = (const float*)d_in[14];
  const float* pm  = (const float*)d_in[15];
  const float* pv  = (const float*)d_in[16];
  float* out = (float*)d_out;
  char* ws = (char*)d_ws;

  u16* xs       = (u16*)ws;
  float* conv   = (float*)(ws + 67108864);
  u16* whlq     = (u16*)(ws + 201326592);
  u16* whlk     = (u16*)(ws + 202375168);
  u16* pwb      = (u16*)(ws + 203423744);
  float* consts = (float*)(ws + 203948032);

  prep_kernel<<<513, 256, 0, stream>>>(qw, kw, pw, qg, qb, qm, qv, kg, kb, km, kv,
                                       pg, pbt, pm, pv, whlq, whlk, pwb, consts);
  lifx_kernel<<<dim3(16, 8, 16), 256, 0, stream>>>(x, xs);
  gemm_kernel<0><<<dim3(8, 4, 64), 256, 0, stream>>>(whlq, 1024, 1024, xs, conv,
                                                     nullptr, nullptr, nullptr);
  qpass_kernel<<<dim3(4, 8, 16), 256, 0, stream>>>(conv, consts, out);
  gemm_kernel<0><<<dim3(8, 4, 64), 256, 0, stream>>>(whlk, 1024, 1024, xs, conv,
                                                     nullptr, nullptr, nullptr);
  kpass_kernel<<<dim3(16, 8, 16), 256, 0, stream>>>(conv, consts, out, xs);  // y overwrites xs
  gemm_kernel<1><<<dim3(8, 4, 64), 256, 0, stream>>>(pwb, 512, 512, xs, nullptr, out,
                                                     pb, consts);
}

// Round 3
// 452.725 us; speedup vs baseline: 1.1859x; 1.0688x over previous
//
#include <hip/hip_runtime.h>

typedef unsigned short u16;
typedef unsigned int u32;
typedef float f32x4 __attribute__((ext_vector_type(4)));
typedef short s16x8 __attribute__((ext_vector_type(8)));

#define T_ 4
#define B_ 16
#define C_ 512
#define N_ 1024
#define YSZ 33554432  // 64*512*1024 (y output elements); attn follows in d_out

// ---- bf16 helpers (manual RNE) ----
__device__ __forceinline__ u16 f2bf(float f) {
  u32 u = __float_as_uint(f);
  u32 r = u + 0x7FFFu + ((u >> 16) & 1u);
  return (u16)(r >> 16);
}
__device__ __forceinline__ float bf2f(u16 h) { return __uint_as_float(((u32)h) << 16); }

// ---- async global->LDS, 16B per lane, wave-uniform LDS base ----
__device__ __forceinline__ void async16(const void* g, void* l) {
  __builtin_amdgcn_global_load_lds((const __attribute__((address_space(1))) void*)g,
                                   (__attribute__((address_space(3))) void*)l, 16, 0, 0);
}

// =====================================================================
// prep: split q_w/k_w into bf16 hi|lo concat [512][1024]; proj_w -> bf16;
//       BN constants (inv, bias) for q/k/p into consts[].
// =====================================================================
__global__ void prep_kernel(const float* __restrict__ qw, const float* __restrict__ kw,
                            const float* __restrict__ pw,
                            const float* __restrict__ qg, const float* __restrict__ qb,
                            const float* __restrict__ qm, const float* __restrict__ qv,
                            const float* __restrict__ kg, const float* __restrict__ kb,
                            const float* __restrict__ km, const float* __restrict__ kv,
                            const float* __restrict__ pg, const float* __restrict__ pbt,
                            const float* __restrict__ pm, const float* __restrict__ pv,
                            u16* __restrict__ whlq, u16* __restrict__ whlk,
                            u16* __restrict__ pwb, float* __restrict__ consts) {
  int blk = blockIdx.x, tid = threadIdx.x;
  if (blk < 512) {
    int d = blk;
    for (int c = tid; c < 512; c += 256) {
      float w = qw[d * 512 + c];
      u16 hi = f2bf(w);
      whlq[d * 1024 + c] = hi;
      whlq[d * 1024 + 512 + c] = f2bf(w - bf2f(hi));
      w = kw[d * 512 + c];
      hi = f2bf(w);
      whlk[d * 1024 + c] = hi;
      whlk[d * 1024 + 512 + c] = f2bf(w - bf2f(hi));
      pwb[d * 512 + c] = f2bf(pw[d * 512 + c]);
    }
  } else {
    for (int c = tid; c < 512; c += 256) {
      float inv = qg[c] / sqrtf(qv[c] + 1e-5f);
      consts[c] = inv; consts[512 + c] = qb[c] - qm[c] * inv;
      inv = kg[c] / sqrtf(kv[c] + 1e-5f);
      consts[1024 + c] = inv; consts[1536 + c] = kb[c] - km[c] * inv;
      inv = pg[c] / sqrtf(pv[c] + 1e-5f);
      consts[2048 + c] = inv; consts[2560 + c] = pbt[c] - pm[c] * inv;
    }
  }
}

// =====================================================================
// lif_x: x[t,b,c,n] f32 -> spikes xs[t,b,n,c] bf16 (LDS transpose).
// =====================================================================
__global__ __launch_bounds__(256) void lifx_kernel(const float* __restrict__ x,
                                                   u16* __restrict__ xs) {
  int b = blockIdx.z;
  int cbase = blockIdx.y * 64, nbase = blockIdx.x * 64;
  int tid = threadIdx.x;
  int c_l = tid >> 6, n_l = tid & 63;
  __shared__ __align__(16) u16 tile[64 * 72];
  float v[16];
#pragma unroll
  for (int i = 0; i < 16; ++i) v[i] = 0.f;
  for (int t = 0; t < 4; ++t) {
    const float* xp = x + ((size_t)(t * 16 + b) * 512 + cbase + c_l * 16) * 1024 + nbase + n_l;
#pragma unroll
    for (int i = 0; i < 16; ++i) {
      float xv = xp[(size_t)i * 1024];
      float vn = v[i] + 0.5f * (xv - v[i]);   // v + (x-v)/TAU, TAU=2 (bit-exact vs np)
      bool s = vn >= 1.0f;
      tile[n_l * 72 + c_l * 16 + i] = s ? 0x3F80 : 0;
      v[i] = s ? 0.f : vn;
    }
    __syncthreads();
    u16* yb = xs + ((size_t)(t * 16 + b) * 1024 + nbase) * 512 + cbase;
#pragma unroll
    for (int e = 0; e < 2; ++e) {
      int chunk = tid * 2 + e;
      int n = chunk >> 3, c0 = (chunk & 7) * 8;
      *(uint4*)&yb[(size_t)n * 512 + c0] = *(const uint4*)&tile[n * 72 + c0];
    }
    __syncthreads();
  }
}

// =====================================================================
// gemm_q: fused conv_q + BN + LIF + head-sum + attn-LIF.
// Grid (n/128, c/128, b). t looped inside; LIF v state in regs.
// Head index within block = wm (each wave-row half covers exactly one
// 64-channel head). qh reduced in-lane over (ti,r), cross-lane over quad
// via shfl_xor(16/32). Writes ONLY attn (f32 0/1) to d_out tail.
// =====================================================================
__global__ __launch_bounds__(256, 2) void gemm_q_kernel(
    const u16* __restrict__ A, const u16* __restrict__ Bbase,
    const float* __restrict__ consts, float* __restrict__ dout) {
  const int tid = threadIdx.x;
  const int lane = tid & 63, w = tid >> 6;
  const int wm = w >> 1, wn = w & 1;
  const int quad = lane >> 4, l16 = lane & 15;
  const int b = blockIdx.z;
  const int m_blk = blockIdx.y * 128, n_blk = blockIdx.x * 128;
  const int srow = lane >> 3;
  const int scol = (((lane & 7) ^ srow) & 7) * 8;
  __shared__ __align__(16) u16 As[128 * 64];
  __shared__ __align__(16) u16 Bs[128 * 64];
  const int rxor = l16 & 7;
  float v[64];  // LIF state, [ti*4+tj]*4+r
#pragma unroll
  for (int i = 0; i < 64; ++i) v[i] = 0.f;
  float va[4] = {0.f, 0.f, 0.f, 0.f};  // attn LIF state per tj

  for (int t = 0; t < 4; ++t) {
    f32x4 acc[4][4];
    const f32x4 zero = {0.f, 0.f, 0.f, 0.f};
#pragma unroll
    for (int i = 0; i < 4; ++i)
#pragma unroll
      for (int j = 0; j < 4; ++j) acc[i][j] = zero;
    const u16* Bt = Bbase + (size_t)(t * 16 + b) * (N_ * C_);

    for (int k0 = 0; k0 < 1024; k0 += 64) {
      int ck0 = k0 & 511;
#pragma unroll
      for (int i = 0; i < 4; ++i) {
        int r = i * 32 + w * 8 + srow;
        async16(A + (size_t)(m_blk + r) * 1024 + k0 + scol, &As[(i * 32 + w * 8) * 64]);
        async16(Bt + (size_t)(n_blk + r) * 512 + ck0 + scol, &Bs[(i * 32 + w * 8) * 64]);
      }
      __syncthreads();
#pragma unroll
      for (int kk = 0; kk < 2; ++kk) {
        s16x8 af[4], bf[4];
        const int slot = ((kk * 4 + quad) ^ rxor) * 8;
#pragma unroll
        for (int ti = 0; ti < 4; ++ti)
          af[ti] = *(const s16x8*)&As[(wm * 64 + ti * 16 + l16) * 64 + slot];
#pragma unroll
        for (int tj = 0; tj < 4; ++tj)
          bf[tj] = *(const s16x8*)&Bs[(wn * 64 + tj * 16 + l16) * 64 + slot];
#pragma unroll
        for (int ti = 0; ti < 4; ++ti)
#pragma unroll
          for (int tj = 0; tj < 4; ++tj)
            acc[ti][tj] = __builtin_amdgcn_mfma_f32_16x16x32_bf16(af[ti], bf[tj], acc[ti][tj], 0, 0, 0);
      }
      __syncthreads();
    }

    // epilogue: BN + LIF + head partial sums
    float qp[4] = {0.f, 0.f, 0.f, 0.f};
#pragma unroll
    for (int ti = 0; ti < 4; ++ti) {
#pragma unroll
      for (int r = 0; r < 4; ++r) {
        int row = m_blk + wm * 64 + ti * 16 + quad * 4 + r;
        float iv = consts[row], ib = consts[512 + row];
#pragma unroll
        for (int tj = 0; tj < 4; ++tj) {
          float bnv = acc[ti][tj][r] * iv + ib;
          float vv = v[(ti * 4 + tj) * 4 + r];
          float vn = vv + 0.5f * (bnv - vv);
          bool s = vn >= 1.0f;
          v[(ti * 4 + tj) * 4 + r] = s ? 0.f : vn;
          qp[tj] += s ? 1.f : 0.f;
        }
      }
    }
    int h = (m_blk >> 6) + wm;
#pragma unroll
    for (int tj = 0; tj < 4; ++tj) {
      float q = qp[tj];
      q += __shfl_xor(q, 16, 64);
      q += __shfl_xor(q, 32, 64);  // sum over quad -> full 64-channel head sum
      float vn = va[tj] + 0.5f * (q - va[tj]);  // exact dyadic
      bool s = vn >= 0.5f;
      va[tj] = s ? 0.f : vn;
      if (quad == 0) {
        int col = n_blk + wn * 64 + tj * 16 + l16;
        dout[(size_t)YSZ + ((size_t)(t * 16 + b) * 8 + h) * 1024 + col] = s ? 1.f : 0.f;
      }
    }
  }
}

// =====================================================================
// gemm_k: fused conv_k + BN + LIF + (spike * attn) -> y[t,b,n,c] bf16.
// Same batching as gemm_q. Transpose via LDS tile aliased onto As/Bs
// (dead after K-loop), stride 132 u16 for bank spread.
// =====================================================================
__global__ __launch_bounds__(256, 2) void gemm_k_kernel(
    const u16* __restrict__ A, const u16* __restrict__ Bbase,
    const float* __restrict__ consts, const float* __restrict__ dout,
    u16* __restrict__ y) {
  const int tid = threadIdx.x;
  const int lane = tid & 63, w = tid >> 6;
  const int wm = w >> 1, wn = w & 1;
  const int quad = lane >> 4, l16 = lane & 15;
  const int b = blockIdx.z;
  const int m_blk = blockIdx.y * 128, n_blk = blockIdx.x * 128;
  const int srow = lane >> 3;
  const int scol = (((lane & 7) ^ srow) & 7) * 8;
  __shared__ __align__(16) u16 smem[128 * 132];  // As|Bs during K-loop, Ys in epilogue
  u16* As = smem;
  u16* Bs = smem + 128 * 64;
  u16* Ys = smem;  // stride 132
  const int rxor = l16 & 7;
  float v[64];
#pragma unroll
  for (int i = 0; i < 64; ++i) v[i] = 0.f;

  for (int t = 0; t < 4; ++t) {
    f32x4 acc[4][4];
    const f32x4 zero = {0.f, 0.f, 0.f, 0.f};
#pragma unroll
    for (int i = 0; i < 4; ++i)
#pragma unroll
      for (int j = 0; j < 4; ++j) acc[i][j] = zero;
    const u16* Bt = Bbase + (size_t)(t * 16 + b) * (N_ * C_);

    for (int k0 = 0; k0 < 1024; k0 += 64) {
      int ck0 = k0 & 511;
#pragma unroll
      for (int i = 0; i < 4; ++i) {
        int r = i * 32 + w * 8 + srow;
        async16(A + (size_t)(m_blk + r) * 1024 + k0 + scol, &As[(i * 32 + w * 8) * 64]);
        async16(Bt + (size_t)(n_blk + r) * 512 + ck0 + scol, &Bs[(i * 32 + w * 8) * 64]);
      }
      __syncthreads();
#pragma unroll
      for (int kk = 0; kk < 2; ++kk) {
        s16x8 af[4], bf[4];
        const int slot = ((kk * 4 + quad) ^ rxor) * 8;
#pragma unroll
        for (int ti = 0; ti < 4; ++ti)
          af[ti] = *(const s16x8*)&As[(wm * 64 + ti * 16 + l16) * 64 + slot];
#pragma unroll
        for (int tj = 0; tj < 4; ++tj)
          bf[tj] = *(const s16x8*)&Bs[(wn * 64 + tj * 16 + l16) * 64 + slot];
#pragma unroll
        for (int ti = 0; ti < 4; ++ti)
#pragma unroll
          for (int tj = 0; tj < 4; ++tj)
            acc[ti][tj] = __builtin_amdgcn_mfma_f32_16x16x32_bf16(af[ti], bf[tj], acc[ti][tj], 0, 0, 0);
      }
      __syncthreads();
    }

    // attn for this block's head/cols
    int h = (m_blk >> 6) + wm;
    float at[4];
#pragma unroll
    for (int tj = 0; tj < 4; ++tj) {
      int col = n_blk + wn * 64 + tj * 16 + l16;
      at[tj] = dout[(size_t)YSZ + ((size_t)(t * 16 + b) * 8 + h) * 1024 + col];
    }

    // epilogue: BN + LIF + mask, pack 4 consecutive c into LDS transpose tile
#pragma unroll
    for (int ti = 0; ti < 4; ++ti) {
      u16 pk[4][4];
#pragma unroll
      for (int r = 0; r < 4; ++r) {
        int row = m_blk + wm * 64 + ti * 16 + quad * 4 + r;
        float iv = consts[1024 + row], ib = consts[1536 + row];
#pragma unroll
        for (int tj = 0; tj < 4; ++tj) {
          float bnv = acc[ti][tj][r] * iv + ib;
          float vv = v[(ti * 4 + tj) * 4 + r];
          float vn = vv + 0.5f * (bnv - vv);
          bool s = vn >= 1.0f;
          v[(ti * 4 + tj) * 4 + r] = s ? 0.f : vn;
          pk[tj][r] = (s && at[tj] != 0.f) ? 0x3F80 : 0;
        }
      }
#pragma unroll
      for (int tj = 0; tj < 4; ++tj) {
        int n_loc = wn * 64 + tj * 16 + l16;
        int c_loc = wm * 64 + ti * 16 + quad * 4;
        u32 lo = (u32)pk[tj][0] | ((u32)pk[tj][1] << 16);
        u32 hi = (u32)pk[tj][2] | ((u32)pk[tj][3] << 16);
        uint2 pv2; pv2.x = lo; pv2.y = hi;
        *(uint2*)&Ys[n_loc * 132 + c_loc] = pv2;
      }
    }
    __syncthreads();
    // coop store: 128 rows x 128 u16 (256B/row) coalesced
    u16* yb = y + ((size_t)(t * 16 + b) * 1024 + n_blk) * 512 + m_blk;
#pragma unroll
    for (int p = 0; p < 8; ++p) {
      int idx = p * 256 + tid;
      int rown = idx >> 4, ch = (idx & 15) * 8;
      *(uint4*)&yb[(size_t)rown * 512 + ch] = *(const uint4*)&Ys[rown * 132 + ch];
    }
    __syncthreads();  // Ys dead before next t's staging overwrites smem
  }
}

// =====================================================================
// gemm_proj: out[d,n] = (sum_k pw[d,k]*y[n,k] + proj_b)*p_inv + p_bias.
// =====================================================================
__global__ __launch_bounds__(256, 3) void gemm_proj_kernel(
    const u16* __restrict__ A, const u16* __restrict__ Bbase,
    float* __restrict__ outP, const float* __restrict__ projb,
    const float* __restrict__ consts) {
  const int tid = threadIdx.x;
  const int lane = tid & 63, w = tid >> 6;
  const int wm = w >> 1, wn = w & 1;
  const int quad = lane >> 4, l16 = lane & 15;
  const int tb = blockIdx.z;
  const int m_blk = blockIdx.y * 128, n_blk = blockIdx.x * 128;
  const int srow = lane >> 3;
  const int scol = (((lane & 7) ^ srow) & 7) * 8;
  __shared__ __align__(16) u16 As[128 * 64];
  __shared__ __align__(16) u16 Bs[128 * 64];
  f32x4 acc[4][4];
  const f32x4 zero = {0.f, 0.f, 0.f, 0.f};
#pragma unroll
  for (int i = 0; i < 4; ++i)
#pragma unroll
    for (int j = 0; j < 4; ++j) acc[i][j] = zero;
  const u16* Bt = Bbase + (size_t)tb * (N_ * C_);
  const int rxor = l16 & 7;

  for (int k0 = 0; k0 < 512; k0 += 64) {
#pragma unroll
    for (int i = 0; i < 4; ++i) {
      int r = i * 32 + w * 8 + srow;
      async16(A + (size_t)(m_blk + r) * 512 + k0 + scol, &As[(i * 32 + w * 8) * 64]);
      async16(Bt + (size_t)(n_blk + r) * 512 + k0 + scol, &Bs[(i * 32 + w * 8) * 64]);
    }
    __syncthreads();
#pragma unroll
    for (int kk = 0; kk < 2; ++kk) {
      s16x8 af[4], bf[4];
      const int slot = ((kk * 4 + quad) ^ rxor) * 8;
#pragma unroll
      for (int ti = 0; ti < 4; ++ti)
        af[ti] = *(const s16x8*)&As[(wm * 64 + ti * 16 + l16) * 64 + slot];
#pragma unroll
      for (int tj = 0; tj < 4; ++tj)
        bf[tj] = *(const s16x8*)&Bs[(wn * 64 + tj * 16 + l16) * 64 + slot];
#pragma unroll
      for (int ti = 0; ti < 4; ++ti)
#pragma unroll
        for (int tj = 0; tj < 4; ++tj)
          acc[ti][tj] = __builtin_amdgcn_mfma_f32_16x16x32_bf16(af[ti], bf[tj], acc[ti][tj], 0, 0, 0);
    }
    __syncthreads();
  }

  const float* pinv = consts + 2048;
  const float* pb2 = consts + 2560;
  float* o = outP + (size_t)tb * (C_ * N_);
#pragma unroll
  for (int ti = 0; ti < 4; ++ti) {
    int row0 = m_blk + wm * 64 + ti * 16 + quad * 4;
#pragma unroll
    for (int r = 0; r < 4; ++r) {
      int row = row0 + r;
      float bi = projb[row], piv = pinv[row], pbi = pb2[row];
#pragma unroll
      for (int tj = 0; tj < 4; ++tj) {
        int col = n_blk + wn * 64 + tj * 16 + l16;
        o[(size_t)row * N_ + col] = (acc[ti][tj][r] + bi) * piv + pbi;
      }
    }
  }
}

// =====================================================================
extern "C" void kernel_launch(void* const* d_in, const int* in_sizes, int n_in,
                              void* d_out, int out_size, void* d_ws, size_t ws_size,
                              hipStream_t stream) {
  const float* x   = (const float*)d_in[0];
  const float* qw  = (const float*)d_in[1];
  const float* qg  = (const float*)d_in[2];
  const float* qb  = (const float*)d_in[3];
  const float* qm  = (const float*)d_in[4];
  const float* qv  = (const float*)d_in[5];
  const float* kw  = (const float*)d_in[6];
  const float* kg  = (const float*)d_in[7];
  const float* kb  = (const float*)d_in[8];
  const float* km  = (const float*)d_in[9];
  const float* kv  = (const float*)d_in[10];
  const float* pw  = (const float*)d_in[11];
  const float* pb  = (const float*)d_in[12];
  const float* pg  = (const float*)d_in[13];
  const float* pbt = (const float*)d_in[14];
  const float* pm  = (const float*)d_in[15];
  const float* pv  = (const float*)d_in[16];
  float* out = (float*)d_out;
  char* ws = (char*)d_ws;

  u16* xs       = (u16*)ws;                    // 64 MB spikes [t,b,n,c]
  u16* y2       = (u16*)(ws + 67108864);       // 64 MB y [t,b,n,c]
  u16* whlq     = (u16*)(ws + 201326592);
  u16* whlk     = (u16*)(ws + 202375168);
  u16* pwb      = (u16*)(ws + 203423744);
  float* consts = (float*)(ws + 203948032);

  prep_kernel<<<513, 256, 0, stream>>>(qw, kw, pw, qg, qb, qm, qv, kg, kb, km, kv,
                                       pg, pbt, pm, pv, whlq, whlk, pwb, consts);
  lifx_kernel<<<dim3(16, 8, 16), 256, 0, stream>>>(x, xs);
  gemm_q_kernel<<<dim3(8, 4, 16), 256, 0, stream>>>(whlq, xs, consts, out);
  gemm_k_kernel<<<dim3(8, 4, 16), 256, 0, stream>>>(whlk, xs, consts, out, y2);
  gemm_proj_kernel<<<dim3(8, 4, 64), 256, 0, stream>>>(pwb, y2, out, pb, consts);
}

// Round 4
// 430.453 us; speedup vs baseline: 1.2472x; 1.0517x over previous
//
#include <hip/hip_runtime.h>

typedef unsigned short u16;
typedef unsigned int u32;
typedef float f32x4 __attribute__((ext_vector_type(4)));
typedef short s16x8 __attribute__((ext_vector_type(8)));

#define T_ 4
#define B_ 16
#define C_ 512
#define N_ 1024
#define YSZ 33554432  // 64*512*1024 (y output elements); attn follows in d_out

// ---- bf16 helpers (manual RNE) ----
__device__ __forceinline__ u16 f2bf(float f) {
  u32 u = __float_as_uint(f);
  u32 r = u + 0x7FFFu + ((u >> 16) & 1u);
  return (u16)(r >> 16);
}
__device__ __forceinline__ float bf2f(u16 h) { return __uint_as_float(((u32)h) << 16); }

// ---- async global->LDS, 16B per lane, wave-uniform LDS base ----
__device__ __forceinline__ void async16(const void* g, void* l) {
  __builtin_amdgcn_global_load_lds((const __attribute__((address_space(1))) void*)g,
                                   (__attribute__((address_space(3))) void*)l, 16, 0, 0);
}

// =====================================================================
// prep: split q_w/k_w into bf16 hi|lo concat [512][1024]; proj_w -> bf16;
//       BN constants (inv, bias) for q/k/p into consts[].
// =====================================================================
__global__ void prep_kernel(const float* __restrict__ qw, const float* __restrict__ kw,
                            const float* __restrict__ pw,
                            const float* __restrict__ qg, const float* __restrict__ qb,
                            const float* __restrict__ qm, const float* __restrict__ qv,
                            const float* __restrict__ kg, const float* __restrict__ kb,
                            const float* __restrict__ km, const float* __restrict__ kv,
                            const float* __restrict__ pg, const float* __restrict__ pbt,
                            const float* __restrict__ pm, const float* __restrict__ pv,
                            u16* __restrict__ whlq, u16* __restrict__ whlk,
                            u16* __restrict__ pwb, float* __restrict__ consts) {
  int blk = blockIdx.x, tid = threadIdx.x;
  if (blk < 512) {
    int d = blk;
    for (int c = tid; c < 512; c += 256) {
      float w = qw[d * 512 + c];
      u16 hi = f2bf(w);
      whlq[d * 1024 + c] = hi;
      whlq[d * 1024 + 512 + c] = f2bf(w - bf2f(hi));
      w = kw[d * 512 + c];
      hi = f2bf(w);
      whlk[d * 1024 + c] = hi;
      whlk[d * 1024 + 512 + c] = f2bf(w - bf2f(hi));
      pwb[d * 512 + c] = f2bf(pw[d * 512 + c]);
    }
  } else {
    for (int c = tid; c < 512; c += 256) {
      float inv = qg[c] / sqrtf(qv[c] + 1e-5f);
      consts[c] = inv; consts[512 + c] = qb[c] - qm[c] * inv;
      inv = kg[c] / sqrtf(kv[c] + 1e-5f);
      consts[1024 + c] = inv; consts[1536 + c] = kb[c] - km[c] * inv;
      inv = pg[c] / sqrtf(pv[c] + 1e-5f);
      consts[2048 + c] = inv; consts[2560 + c] = pbt[c] - pm[c] * inv;
    }
  }
}

// =====================================================================
// lif_x: x[t,b,c,n] f32 -> spikes xs[t,b,n,c] bf16 (LDS transpose).
// =====================================================================
__global__ __launch_bounds__(256) void lifx_kernel(const float* __restrict__ x,
                                                   u16* __restrict__ xs) {
  int b = blockIdx.z;
  int cbase = blockIdx.y * 64, nbase = blockIdx.x * 64;
  int tid = threadIdx.x;
  int c_l = tid >> 6, n_l = tid & 63;
  __shared__ __align__(16) u16 tile[64 * 72];
  float v[16];
#pragma unroll
  for (int i = 0; i < 16; ++i) v[i] = 0.f;
  for (int t = 0; t < 4; ++t) {
    const float* xp = x + ((size_t)(t * 16 + b) * 512 + cbase + c_l * 16) * 1024 + nbase + n_l;
#pragma unroll
    for (int i = 0; i < 16; ++i) {
      float xv = xp[(size_t)i * 1024];
      float vn = v[i] + 0.5f * (xv - v[i]);   // v + (x-v)/TAU, TAU=2 (bit-exact vs np)
      bool s = vn >= 1.0f;
      tile[n_l * 72 + c_l * 16 + i] = s ? 0x3F80 : 0;
      v[i] = s ? 0.f : vn;
    }
    __syncthreads();
    u16* yb = xs + ((size_t)(t * 16 + b) * 1024 + nbase) * 512 + cbase;
#pragma unroll
    for (int e = 0; e < 2; ++e) {
      int chunk = tid * 2 + e;
      int n = chunk >> 3, c0 = (chunk & 7) * 8;
      *(uint4*)&yb[(size_t)n * 512 + c0] = *(const uint4*)&tile[n * 72 + c0];
    }
    __syncthreads();
  }
}

// =====================================================================
// gemm_q: fused conv_q + BN + LIF + head-sum + attn-LIF.
// K-loop: hi/lo weight halves interleaved per 64-chunk — B tile staged
// ONCE and its fragments shared by hi+lo MFMAs (64 MFMA per barrier-pair,
// 48 KB staged vs 64 KB for the same FLOPs in the K=1024 formulation).
// =====================================================================
__global__ __launch_bounds__(256, 2) void gemm_q_kernel(
    const u16* __restrict__ A, const u16* __restrict__ Bbase,
    const float* __restrict__ consts, float* __restrict__ dout) {
  const int tid = threadIdx.x;
  const int lane = tid & 63, w = tid >> 6;
  const int wm = w >> 1, wn = w & 1;
  const int quad = lane >> 4, l16 = lane & 15;
  const int b = blockIdx.z;
  const int m_blk = blockIdx.y * 128, n_blk = blockIdx.x * 128;
  const int srow = lane >> 3;
  const int scol = (((lane & 7) ^ srow) & 7) * 8;
  __shared__ __align__(16) u16 smem[3 * 128 * 64];  // As_hi | As_lo | Bs
  u16* Ash = smem;
  u16* Asl = smem + 8192;
  u16* Bs  = smem + 16384;
  const int rxor = l16 & 7;
  float v[64];  // LIF state, [ti*4+tj]*4+r
#pragma unroll
  for (int i = 0; i < 64; ++i) v[i] = 0.f;
  float va[4] = {0.f, 0.f, 0.f, 0.f};  // attn LIF state per tj

  for (int t = 0; t < 4; ++t) {
    f32x4 acc[4][4];
    const f32x4 zero = {0.f, 0.f, 0.f, 0.f};
#pragma unroll
    for (int i = 0; i < 4; ++i)
#pragma unroll
      for (int j = 0; j < 4; ++j) acc[i][j] = zero;
    const u16* Bt = Bbase + (size_t)(t * 16 + b) * (N_ * C_);

    for (int k0 = 0; k0 < 512; k0 += 64) {
#pragma unroll
      for (int i = 0; i < 4; ++i) {
        int r = i * 32 + w * 8 + srow;
        int lo = (i * 32 + w * 8) * 64;
        async16(A + (size_t)(m_blk + r) * 1024 + k0 + scol, &Ash[lo]);
        async16(A + (size_t)(m_blk + r) * 1024 + 512 + k0 + scol, &Asl[lo]);
        async16(Bt + (size_t)(n_blk + r) * 512 + k0 + scol, &Bs[lo]);
      }
      __syncthreads();
#pragma unroll
      for (int kk = 0; kk < 2; ++kk) {
        s16x8 ah[4], al[4], bf[4];
        const int slot = ((kk * 4 + quad) ^ rxor) * 8;
#pragma unroll
        for (int ti = 0; ti < 4; ++ti) {
          ah[ti] = *(const s16x8*)&Ash[(wm * 64 + ti * 16 + l16) * 64 + slot];
          al[ti] = *(const s16x8*)&Asl[(wm * 64 + ti * 16 + l16) * 64 + slot];
        }
#pragma unroll
        for (int tj = 0; tj < 4; ++tj)
          bf[tj] = *(const s16x8*)&Bs[(wn * 64 + tj * 16 + l16) * 64 + slot];
#pragma unroll
        for (int ti = 0; ti < 4; ++ti)
#pragma unroll
          for (int tj = 0; tj < 4; ++tj) {
            acc[ti][tj] = __builtin_amdgcn_mfma_f32_16x16x32_bf16(ah[ti], bf[tj], acc[ti][tj], 0, 0, 0);
            acc[ti][tj] = __builtin_amdgcn_mfma_f32_16x16x32_bf16(al[ti], bf[tj], acc[ti][tj], 0, 0, 0);
          }
      }
      __syncthreads();
    }

    // epilogue: BN + LIF + head partial sums
    float qp[4] = {0.f, 0.f, 0.f, 0.f};
#pragma unroll
    for (int ti = 0; ti < 4; ++ti) {
#pragma unroll
      for (int r = 0; r < 4; ++r) {
        int row = m_blk + wm * 64 + ti * 16 + quad * 4 + r;
        float iv = consts[row], ib = consts[512 + row];
#pragma unroll
        for (int tj = 0; tj < 4; ++tj) {
          float bnv = acc[ti][tj][r] * iv + ib;
          float vv = v[(ti * 4 + tj) * 4 + r];
          float vn = vv + 0.5f * (bnv - vv);
          bool s = vn >= 1.0f;
          v[(ti * 4 + tj) * 4 + r] = s ? 0.f : vn;
          qp[tj] += s ? 1.f : 0.f;
        }
      }
    }
    int h = (m_blk >> 6) + wm;
#pragma unroll
    for (int tj = 0; tj < 4; ++tj) {
      float q = qp[tj];
      q += __shfl_xor(q, 16, 64);
      q += __shfl_xor(q, 32, 64);  // sum over quad -> full 64-channel head sum
      float vn = va[tj] + 0.5f * (q - va[tj]);  // exact dyadic
      bool s = vn >= 0.5f;
      va[tj] = s ? 0.f : vn;
      if (quad == 0) {
        int col = n_blk + wn * 64 + tj * 16 + l16;
        dout[(size_t)YSZ + ((size_t)(t * 16 + b) * 8 + h) * 1024 + col] = s ? 1.f : 0.f;
      }
    }
  }
}

// =====================================================================
// gemm_k: fused conv_k + BN + LIF + (spike * attn) -> y[t,b,n,c] bf16.
// Same interleaved hi/lo K-loop. Transpose via LDS tile aliased onto the
// staging buffers (dead after K-loop), stride 132 u16 for bank spread.
// =====================================================================
__global__ __launch_bounds__(256, 2) void gemm_k_kernel(
    const u16* __restrict__ A, const u16* __restrict__ Bbase,
    const float* __restrict__ consts, const float* __restrict__ dout,
    u16* __restrict__ y) {
  const int tid = threadIdx.x;
  const int lane = tid & 63, w = tid >> 6;
  const int wm = w >> 1, wn = w & 1;
  const int quad = lane >> 4, l16 = lane & 15;
  const int b = blockIdx.z;
  const int m_blk = blockIdx.y * 128, n_blk = blockIdx.x * 128;
  const int srow = lane >> 3;
  const int scol = (((lane & 7) ^ srow) & 7) * 8;
  __shared__ __align__(16) u16 smem[3 * 128 * 64];  // As_hi | As_lo | Bs ; Ys in epilogue
  u16* Ash = smem;
  u16* Asl = smem + 8192;
  u16* Bs  = smem + 16384;
  u16* Ys  = smem;  // stride 132
  const int rxor = l16 & 7;
  float v[64];
#pragma unroll
  for (int i = 0; i < 64; ++i) v[i] = 0.f;

  for (int t = 0; t < 4; ++t) {
    f32x4 acc[4][4];
    const f32x4 zero = {0.f, 0.f, 0.f, 0.f};
#pragma unroll
    for (int i = 0; i < 4; ++i)
#pragma unroll
      for (int j = 0; j < 4; ++j) acc[i][j] = zero;
    const u16* Bt = Bbase + (size_t)(t * 16 + b) * (N_ * C_);

    for (int k0 = 0; k0 < 512; k0 += 64) {
#pragma unroll
      for (int i = 0; i < 4; ++i) {
        int r = i * 32 + w * 8 + srow;
        int lo = (i * 32 + w * 8) * 64;
        async16(A + (size_t)(m_blk + r) * 1024 + k0 + scol, &Ash[lo]);
        async16(A + (size_t)(m_blk + r) * 1024 + 512 + k0 + scol, &Asl[lo]);
        async16(Bt + (size_t)(n_blk + r) * 512 + k0 + scol, &Bs[lo]);
      }
      __syncthreads();
#pragma unroll
      for (int kk = 0; kk < 2; ++kk) {
        s16x8 ah[4], al[4], bf[4];
        const int slot = ((kk * 4 + quad) ^ rxor) * 8;
#pragma unroll
        for (int ti = 0; ti < 4; ++ti) {
          ah[ti] = *(const s16x8*)&Ash[(wm * 64 + ti * 16 + l16) * 64 + slot];
          al[ti] = *(const s16x8*)&Asl[(wm * 64 + ti * 16 + l16) * 64 + slot];
        }
#pragma unroll
        for (int tj = 0; tj < 4; ++tj)
          bf[tj] = *(const s16x8*)&Bs[(wn * 64 + tj * 16 + l16) * 64 + slot];
#pragma unroll
        for (int ti = 0; ti < 4; ++ti)
#pragma unroll
          for (int tj = 0; tj < 4; ++tj) {
            acc[ti][tj] = __builtin_amdgcn_mfma_f32_16x16x32_bf16(ah[ti], bf[tj], acc[ti][tj], 0, 0, 0);
            acc[ti][tj] = __builtin_amdgcn_mfma_f32_16x16x32_bf16(al[ti], bf[tj], acc[ti][tj], 0, 0, 0);
          }
      }
      __syncthreads();
    }

    // attn for this block's head/cols
    int h = (m_blk >> 6) + wm;
    float at[4];
#pragma unroll
    for (int tj = 0; tj < 4; ++tj) {
      int col = n_blk + wn * 64 + tj * 16 + l16;
      at[tj] = dout[(size_t)YSZ + ((size_t)(t * 16 + b) * 8 + h) * 1024 + col];
    }

    // epilogue: BN + LIF + mask, pack 4 consecutive c into LDS transpose tile
#pragma unroll
    for (int ti = 0; ti < 4; ++ti) {
      u16 pk[4][4];
#pragma unroll
      for (int r = 0; r < 4; ++r) {
        int row = m_blk + wm * 64 + ti * 16 + quad * 4 + r;
        float iv = consts[1024 + row], ib = consts[1536 + row];
#pragma unroll
        for (int tj = 0; tj < 4; ++tj) {
          float bnv = acc[ti][tj][r] * iv + ib;
          float vv = v[(ti * 4 + tj) * 4 + r];
          float vn = vv + 0.5f * (bnv - vv);
          bool s = vn >= 1.0f;
          v[(ti * 4 + tj) * 4 + r] = s ? 0.f : vn;
          pk[tj][r] = (s && at[tj] != 0.f) ? 0x3F80 : 0;
        }
      }
#pragma unroll
      for (int tj = 0; tj < 4; ++tj) {
        int n_loc = wn * 64 + tj * 16 + l16;
        int c_loc = wm * 64 + ti * 16 + quad * 4;
        u32 lo2 = (u32)pk[tj][0] | ((u32)pk[tj][1] << 16);
        u32 hi2 = (u32)pk[tj][2] | ((u32)pk[tj][3] << 16);
        uint2 pv2; pv2.x = lo2; pv2.y = hi2;
        *(uint2*)&Ys[n_loc * 132 + c_loc] = pv2;
      }
    }
    __syncthreads();
    // coop store: 128 rows x 128 u16 (256B/row) coalesced
    u16* yb = y + ((size_t)(t * 16 + b) * 1024 + n_blk) * 512 + m_blk;
#pragma unroll
    for (int p = 0; p < 8; ++p) {
      int idx = p * 256 + tid;
      int rown = idx >> 4, ch = (idx & 15) * 8;
      *(uint4*)&yb[(size_t)rown * 512 + ch] = *(const uint4*)&Ys[rown * 132 + ch];
    }
    __syncthreads();  // Ys dead before next t's staging overwrites smem
  }
}

// =====================================================================
// gemm_proj: out[d,n] = (sum_k pw[d,k]*y[n,k] + proj_b)*p_inv + p_bias.
// =====================================================================
__global__ __launch_bounds__(256, 3) void gemm_proj_kernel(
    const u16* __restrict__ A, const u16* __restrict__ Bbase,
    float* __restrict__ outP, const float* __restrict__ projb,
    const float* __restrict__ consts) {
  const int tid = threadIdx.x;
  const int lane = tid & 63, w = tid >> 6;
  const int wm = w >> 1, wn = w & 1;
  const int quad = lane >> 4, l16 = lane & 15;
  const int tb = blockIdx.z;
  const int m_blk = blockIdx.y * 128, n_blk = blockIdx.x * 128;
  const int srow = lane >> 3;
  const int scol = (((lane & 7) ^ srow) & 7) * 8;
  __shared__ __align__(16) u16 As[128 * 64];
  __shared__ __align__(16) u16 Bs[128 * 64];
  f32x4 acc[4][4];
  const f32x4 zero = {0.f, 0.f, 0.f, 0.f};
#pragma unroll
  for (int i = 0; i < 4; ++i)
#pragma unroll
    for (int j = 0; j < 4; ++j) acc[i][j] = zero;
  const u16* Bt = Bbase + (size_t)tb * (N_ * C_);
  const int rxor = l16 & 7;

  for (int k0 = 0; k0 < 512; k0 += 64) {
#pragma unroll
    for (int i = 0; i < 4; ++i) {
      int r = i * 32 + w * 8 + srow;
      async16(A + (size_t)(m_blk + r) * 512 + k0 + scol, &As[(i * 32 + w * 8) * 64]);
      async16(Bt + (size_t)(n_blk + r) * 512 + k0 + scol, &Bs[(i * 32 + w * 8) * 64]);
    }
    __syncthreads();
#pragma unroll
    for (int kk = 0; kk < 2; ++kk) {
      s16x8 af[4], bf[4];
      const int slot = ((kk * 4 + quad) ^ rxor) * 8;
#pragma unroll
      for (int ti = 0; ti < 4; ++ti)
        af[ti] = *(const s16x8*)&As[(wm * 64 + ti * 16 + l16) * 64 + slot];
#pragma unroll
      for (int tj = 0; tj < 4; ++tj)
        bf[tj] = *(const s16x8*)&Bs[(wn * 64 + tj * 16 + l16) * 64 + slot];
#pragma unroll
      for (int ti = 0; ti < 4; ++ti)
#pragma unroll
        for (int tj = 0; tj < 4; ++tj)
          acc[ti][tj] = __builtin_amdgcn_mfma_f32_16x16x32_bf16(af[ti], bf[tj], acc[ti][tj], 0, 0, 0);
    }
    __syncthreads();
  }

  const float* pinv = consts + 2048;
  const float* pb2 = consts + 2560;
  float* o = outP + (size_t)tb * (C_ * N_);
#pragma unroll
  for (int ti = 0; ti < 4; ++ti) {
    int row0 = m_blk + wm * 64 + ti * 16 + quad * 4;
#pragma unroll
    for (int r = 0; r < 4; ++r) {
      int row = row0 + r;
      float bi = projb[row], piv = pinv[row], pbi = pb2[row];
#pragma unroll
      for (int tj = 0; tj < 4; ++tj) {
        int col = n_blk + wn * 64 + tj * 16 + l16;
        o[(size_t)row * N_ + col] = (acc[ti][tj][r] + bi) * piv + pbi;
      }
    }
  }
}

// =====================================================================
extern "C" void kernel_launch(void* const* d_in, const int* in_sizes, int n_in,
                              void* d_out, int out_size, void* d_ws, size_t ws_size,
                              hipStream_t stream) {
  const float* x   = (const float*)d_in[0];
  const float* qw  = (const float*)d_in[1];
  const float* qg  = (const float*)d_in[2];
  const float* qb  = (const float*)d_in[3];
  const float* qm  = (const float*)d_in[4];
  const float* qv  = (const float*)d_in[5];
  const float* kw  = (const float*)d_in[6];
  const float* kg  = (const float*)d_in[7];
  const float* kb  = (const float*)d_in[8];
  const float* km  = (const float*)d_in[9];
  const float* kv  = (const float*)d_in[10];
  const float* pw  = (const float*)d_in[11];
  const float* pb  = (const float*)d_in[12];
  const float* pg  = (const float*)d_in[13];
  const float* pbt = (const float*)d_in[14];
  const float* pm  = (const float*)d_in[15];
  const float* pv  = (const float*)d_in[16];
  float* out = (float*)d_out;
  char* ws = (char*)d_ws;

  u16* xs       = (u16*)ws;                    // 64 MB spikes [t,b,n,c]
  u16* y2       = (u16*)(ws + 67108864);       // 64 MB y [t,b,n,c]
  u16* whlq     = (u16*)(ws + 201326592);
  u16* whlk     = (u16*)(ws + 202375168);
  u16* pwb      = (u16*)(ws + 203423744);
  float* consts = (float*)(ws + 203948032);

  prep_kernel<<<513, 256, 0, stream>>>(qw, kw, pw, qg, qb, qm, qv, kg, kb, km, kv,
                                       pg, pbt, pm, pv, whlq, whlk, pwb, consts);
  lifx_kernel<<<dim3(16, 8, 16), 256, 0, stream>>>(x, xs);
  gemm_q_kernel<<<dim3(8, 4, 16), 256, 0, stream>>>(whlq, xs, consts, out);
  gemm_k_kernel<<<dim3(8, 4, 16), 256, 0, stream>>>(whlk, xs, consts, out, y2);
  gemm_proj_kernel<<<dim3(8, 4, 64), 256, 0, stream>>>(pwb, y2, out, pb, consts);
}